// Round 2
// baseline (424.874 us; speedup 1.0000x reference)
//
#include <hip/hip_runtime.h>

#define CH    128
#define HH    64
#define WW    96
#define MD    40
#define KD    81
#define HW    (HH*WW)          /* 6144 */
#define CHW   (CH*HW)
#define SCALE 0.08838834764831845f   /* 1/sqrt(128) */
#define LSTR  72               /* ushorts per row: 64 bf16 + 8 pad (16B-aligned rows) */
#define CHUNK (WW*LSTR)        /* 6912 ushorts = 13824 B per (b,y,h) per tensor */
#define WS2_USH ((size_t)2*HH*2*CHUNK)  /* x2 region offset in ushorts */
#define NWG   (HH*KD*2)        /* 10368 blocks, divisible by 8 */
#define CPX   (NWG/8)          /* 1296 blocks per XCD chunk */

typedef __attribute__((ext_vector_type(8))) short bf16x8;
typedef __attribute__((ext_vector_type(4))) float f32x4;

__device__ inline unsigned int pack2bf(float lo, float hi) {
    unsigned int a = __float_as_uint(lo), b = __float_as_uint(hi);
    a = (a + 0x7FFFu + ((a >> 16) & 1u)) >> 16;   // RTN bf16
    b = (b + 0x7FFFu + ((b >> 16) & 1u)) >> 16;
    return a | (b << 16);
}

__device__ __forceinline__ void gload16(const void* g, void* l) {
    __builtin_amdgcn_global_load_lds(
        (const __attribute__((address_space(1))) void*)g,
        (__attribute__((address_space(3))) void*)l, 16, 0, 0);
}

// ---------------------------------------------------------------------------
// Pre-pass: transpose+convert x1,x2 rows to bf16 workspace, [b][y][h][x][72].
// ---------------------------------------------------------------------------
__global__ __launch_bounds__(256) void prepack(
    const float* __restrict__ x1, const float* __restrict__ x2,
    unsigned short* __restrict__ ws)
{
    const int y = blockIdx.x;
    const int h = blockIdx.y & 1;
    const int t = blockIdx.y >> 1;
    const int b = blockIdx.z;

    const float* src = (t ? x2 : x1)
        + (size_t)b * CHW + (size_t)(h * 64) * HW + (size_t)y * WW;
    unsigned short* dst = ws + (size_t)t * WS2_USH
        + ((size_t)(b * HH + y) * 2 + h) * CHUNK;

    for (int j = threadIdx.x; j < 8 * WW; j += 256) {   // 3 iters
        const int cg = j / WW;                          // channel octet 0..7
        const int x  = j - cg * WW;
        const float* p = src + (size_t)(cg * 8) * HW + x;
        float f[8];
        #pragma unroll
        for (int i = 0; i < 8; ++i) f[i] = p[(size_t)i * HW];
        uint4 w;
        w.x = pack2bf(f[0], f[1]); w.y = pack2bf(f[2], f[3]);
        w.z = pack2bf(f[4], f[5]); w.w = pack2bf(f[6], f[7]);
        *reinterpret_cast<uint4*>(&dst[(size_t)x * LSTR + cg * 8]) = w;
    }
}

__device__ __forceinline__ void mfma_half(
    const unsigned short* sA, const unsigned short* sB,
    int m0, int n0, int lr, int q, f32x4 (&acc)[3][3])
{
    #pragma unroll
    for (int kk = 0; kk < 2; ++kk) {
        const int cl = kk * 32 + q * 8;
        bf16x8 af[3], bg[3];
        #pragma unroll
        for (int i = 0; i < 3; ++i)
            af[i] = *reinterpret_cast<const bf16x8*>(&sB[(m0 + 16 * i + lr) * LSTR + cl]);
        #pragma unroll
        for (int j = 0; j < 3; ++j)
            bg[j] = *reinterpret_cast<const bf16x8*>(&sA[(n0 + 16 * j + lr) * LSTR + cl]);
        #pragma unroll
        for (int i = 0; i < 3; ++i)
            #pragma unroll
            for (int j = 0; j < 3; ++j)
                acc[i][j] = __builtin_amdgcn_mfma_f32_16x16x32_bf16(
                    af[i], bg[j], acc[i][j], 0, 0, 0);
    }
}

// ---------------------------------------------------------------------------
// Main: flat grid, XCD-swizzled so each XCD works a contiguous (b,dy,y) range
// (working set ~3 MB -> per-XCD-L2-resident workspace reads).
// Half 0 staged via global_load_lds; half 1 prefetched to registers at kernel
// start (T14) and ds_written after half-0 fragment reads -> only ONE exposed
// global-latency drain per block instead of two.
// ---------------------------------------------------------------------------
__global__ __launch_bounds__(256, 4) void corr_kernel(
    const unsigned short* __restrict__ ws, float* __restrict__ out)
{
    const int bid = blockIdx.x;
    const int wg  = (bid & 7) * CPX + (bid >> 3);   // bijective XCD swizzle
    const int b   = (wg >= HH * KD) ? 1 : 0;
    const int rem = wg - b * (HH * KD);
    const int dy  = rem >> 6;          // KD*HH ordering: y fastest (HH=64)
    const int y   = rem & 63;
    const int tid = threadIdx.x;

    float* outbase = out + ((size_t)b * (KD * KD) + (size_t)dy * KD) * HW
                         + (size_t)y * WW;

    const int y2 = y + dy - MD;
    if (y2 < 0 || y2 >= HH) {
        const float4 z = make_float4(0.f, 0.f, 0.f, 0.f);
        for (int f = tid; f < KD * (WW / 4); f += 256) {
            const int dx = f / (WW / 4);
            const int x4 = f - dx * (WW / 4);
            *reinterpret_cast<float4*>(outbase + (size_t)dx * HW + x4 * 4) = z;
        }
        return;
    }

    // Union LDS: staging (2 x 6912 ush = 27648 B) overlapped with
    // G (96x96 fp32 = 36864 B). 36864 B -> 4 blocks/CU.
    __shared__ __align__(16) char smem[WW * WW * 4];
    unsigned short* sStage = reinterpret_cast<unsigned short*>(smem);
    unsigned short* sA = sStage;            // x1 row, [x][c-half]
    unsigned short* sB = sStage + CHUNK;    // x2 row, [x2][c-half]
    float*          sG = reinterpret_cast<float*>(smem);   // G[x2][x] swizzled

    const unsigned short* wsA = ws + ((size_t)(b * HH + y ) * 2) * CHUNK;
    const unsigned short* wsB = ws + WS2_USH + ((size_t)(b * HH + y2) * 2) * CHUNK;

    const int lane = tid & 63;
    const int wave = tid >> 6;
    const int m0   = (wave >> 1) * 48;   // x2-tile base for this wave
    const int n0   = (wave & 1) * 48;    // x-tile base
    const int lr   = lane & 15;
    const int q    = lane >> 4;

    // --- Issue half-0 staging (direct to LDS) ---
    #pragma unroll
    for (int it = 0; it < 7; ++it) {
        const int idx = it * 256 + tid;
        if (idx < 2 * (CHUNK / 8)) {                 // 1728
            const unsigned short* g = (idx < (CHUNK / 8))
                ? wsA + (size_t)idx * 8
                : wsB + (size_t)(idx - (CHUNK / 8)) * 8;
            gload16(g, sStage + (size_t)idx * 8);
        }
    }
    // --- Issue half-1 prefetch into registers (T14 issue-early) ---
    uint4 pf[7];
    {
        const unsigned short* g1b = wsA + CHUNK;
        const unsigned short* g2b = wsB + CHUNK;
        #pragma unroll
        for (int it = 0; it < 7; ++it) {
            const int idx = it * 256 + tid;
            if (idx < 2 * (CHUNK / 8)) {
                const unsigned short* g = (idx < (CHUNK / 8))
                    ? g1b + (size_t)idx * 8
                    : g2b + (size_t)(idx - (CHUNK / 8)) * 8;
                pf[it] = *reinterpret_cast<const uint4*>(g);
            }
        }
    }

    f32x4 acc[3][3];
    #pragma unroll
    for (int i = 0; i < 3; ++i)
        #pragma unroll
        for (int j = 0; j < 3; ++j)
            acc[i][j] = (f32x4){0.f, 0.f, 0.f, 0.f};

    __syncthreads();                 // drains vmcnt: half0 in LDS, half1 in regs
    mfma_half(sA, sB, m0, n0, lr, q, acc);
    __syncthreads();                 // half-0 fragment reads done

    // --- Write-late: half 1 regs -> LDS (same linear layout) ---
    #pragma unroll
    for (int it = 0; it < 7; ++it) {
        const int idx = it * 256 + tid;
        if (idx < 2 * (CHUNK / 8))
            *reinterpret_cast<uint4*>(sStage + (size_t)idx * 8) = pf[it];
    }
    __syncthreads();
    mfma_half(sA, sB, m0, n0, lr, q, acc);

    __syncthreads();                 // all fragment reads done; smem becomes G
    // D layout: col = lane&15 (=x), row = q*4+r (=x2 within tile).
    // XOR-swizzle: word = row*96+col ^ (row&7)<<2 -> conflict-free write+read.
    #pragma unroll
    for (int i = 0; i < 3; ++i) {
        #pragma unroll
        for (int j = 0; j < 3; ++j) {
            const int col  = n0 + 16 * j + lr;
            const int rowb = m0 + 16 * i + q * 4;
            #pragma unroll
            for (int r = 0; r < 4; ++r) {
                const int row = rowb + r;
                sG[(row * WW + col) ^ ((row & 7) << 2)] = acc[i][j][r];
            }
        }
    }
    __syncthreads();

    // Emit 81 x 96 slab: out[dx][x] = G[x+dx-40][x] * SCALE (0 outside band).
    int dx = tid / WW;                   // 0..2
    int x  = tid - dx * WW;
    #pragma unroll 1
    for (int it = 0; it < 31; ++it) {
        if (dx < KD) {
            const int x2v   = x + dx - MD;
            const bool valid = ((unsigned)x2v < (unsigned)WW);
            const int w     = valid ? ((x2v * WW + x) ^ ((x2v & 7) << 2)) : 0;
            float v = sG[w] * SCALE;
            v = valid ? v : 0.f;
            outbase[(size_t)(dx * HW + x)] = v;
        }
        x += 64; dx += 2;
        if (x >= WW) { x -= WW; ++dx; }
    }
}

extern "C" void kernel_launch(void* const* d_in, const int* in_sizes, int n_in,
                              void* d_out, int out_size, void* d_ws, size_t ws_size,
                              hipStream_t stream) {
    const float* x1 = (const float*)d_in[0];
    const float* x2 = (const float*)d_in[1];
    float* out = (float*)d_out;
    unsigned short* ws = (unsigned short*)d_ws;

    hipLaunchKernelGGL(prepack, dim3(HH, 4, 2), dim3(256), 0, stream, x1, x2, ws);

    hipLaunchKernelGGL(corr_kernel, dim3(NWG), dim3(256), 0, stream, ws, out);
}

// Round 4
// 346.790 us; speedup vs baseline: 1.2252x; 1.2252x over previous
//
#include <hip/hip_runtime.h>

#define CH    128
#define HH    64
#define WW    96
#define MD    40
#define KD    81
#define HW    (HH*WW)          /* 6144 */
#define CHW   (CH*HW)
#define SCALE 0.08838834764831845f   /* 1/sqrt(128) */
#define LSTR  72               /* ushorts per row: 64 bf16 + 8 pad (16B-aligned rows) */
#define CHUNK (WW*LSTR)        /* 6912 ushorts = 13824 B per (b,y,h) per tensor */
#define WS2_USH ((size_t)2*HH*2*CHUNK)  /* x2 region offset in ushorts */
#define NWG   (HH*KD*2)        /* 10368 blocks, divisible by 8 */
#define CPX   (NWG/8)          /* 1296 blocks per XCD chunk */

typedef __attribute__((ext_vector_type(8))) short bf16x8;
typedef __attribute__((ext_vector_type(4))) float f32x4;

__device__ inline unsigned int pack2bf(float lo, float hi) {
    unsigned int a = __float_as_uint(lo), b = __float_as_uint(hi);
    a = (a + 0x7FFFu + ((a >> 16) & 1u)) >> 16;   // RTN bf16
    b = (b + 0x7FFFu + ((b >> 16) & 1u)) >> 16;
    return a | (b << 16);
}

__device__ __forceinline__ void gload16(const void* g, void* l) {
    __builtin_amdgcn_global_load_lds(
        (const __attribute__((address_space(1))) void*)g,
        (__attribute__((address_space(3))) void*)l, 16, 0, 0);
}

// ---------------------------------------------------------------------------
// Pre-pass: transpose+convert x1,x2 rows to bf16 workspace, [b][y][h][x][72].
// ---------------------------------------------------------------------------
__global__ __launch_bounds__(256) void prepack(
    const float* __restrict__ x1, const float* __restrict__ x2,
    unsigned short* __restrict__ ws)
{
    const int y = blockIdx.x;
    const int h = blockIdx.y & 1;
    const int t = blockIdx.y >> 1;
    const int b = blockIdx.z;

    const float* src = (t ? x2 : x1)
        + (size_t)b * CHW + (size_t)(h * 64) * HW + (size_t)y * WW;
    unsigned short* dst = ws + (size_t)t * WS2_USH
        + ((size_t)(b * HH + y) * 2 + h) * CHUNK;

    for (int j = threadIdx.x; j < 8 * WW; j += 256) {   // 3 iters
        const int cg = j / WW;                          // channel octet 0..7
        const int x  = j - cg * WW;
        const float* p = src + (size_t)(cg * 8) * HW + x;
        float f[8];
        #pragma unroll
        for (int i = 0; i < 8; ++i) f[i] = p[(size_t)i * HW];
        uint4 w;
        w.x = pack2bf(f[0], f[1]); w.y = pack2bf(f[2], f[3]);
        w.z = pack2bf(f[4], f[5]); w.w = pack2bf(f[6], f[7]);
        *reinterpret_cast<uint4*>(&dst[(size_t)x * LSTR + cg * 8]) = w;
    }
}

__device__ __forceinline__ void mfma_half(
    const unsigned short* sA, const unsigned short* sB,
    int m0, int n0, int lr, int q, f32x4 (&acc)[3][3])
{
    #pragma unroll
    for (int kk = 0; kk < 2; ++kk) {
        const int cl = kk * 32 + q * 8;
        bf16x8 af[3], bg[3];
        #pragma unroll
        for (int i = 0; i < 3; ++i)
            af[i] = *reinterpret_cast<const bf16x8*>(&sB[(m0 + 16 * i + lr) * LSTR + cl]);
        #pragma unroll
        for (int j = 0; j < 3; ++j)
            bg[j] = *reinterpret_cast<const bf16x8*>(&sA[(n0 + 16 * j + lr) * LSTR + cl]);
        #pragma unroll
        for (int i = 0; i < 3; ++i)
            #pragma unroll
            for (int j = 0; j < 3; ++j)
                acc[i][j] = __builtin_amdgcn_mfma_f32_16x16x32_bf16(
                    af[i], bg[j], acc[i][j], 0, 0, 0);
    }
}

// ---------------------------------------------------------------------------
// Main: flat grid, bijective XCD swizzle (contiguous (b,dy,y) range per XCD ->
// workspace reads L2-resident). Two-phase global_load_lds staging (register
// prefetch spilled under the 128-VGPR cap in R1 -> removed).
// G written band-folded as sD[dx][x] (dx = x2-x+40, only 0..80 kept),
// XOR-swizzled (((dx>>2)&1)<<4 words) -> conflict-free write; emit is a LINEAR
// ds_read_b128 + float4 store (8 iters, was 31 scalar iters).
// R3 fix: zero-fill branch is STRIDED again (R2 wrote it contiguous -> trashed
// neighboring y-rows' output; absmax 4.06).
// ---------------------------------------------------------------------------
__global__ __launch_bounds__(256, 4) void corr_kernel(
    const unsigned short* __restrict__ ws, float* __restrict__ out)
{
    const int bid = blockIdx.x;
    const int wg  = (bid & 7) * CPX + (bid >> 3);   // bijective XCD swizzle
    const int b   = (wg >= HH * KD) ? 1 : 0;
    const int rem = wg - b * (HH * KD);
    const int dy  = rem >> 6;          // (b, dy, y) with y fastest (HH=64)
    const int y   = rem & 63;
    const int tid = threadIdx.x;

    float* outbase = out + ((size_t)b * (KD * KD) + (size_t)dy * KD) * HW
                         + (size_t)y * WW;

    const int y2 = y + dy - MD;
    if (y2 < 0 || y2 >= HH) {
        const float4 z = make_float4(0.f, 0.f, 0.f, 0.f);
        #pragma unroll
        for (int it = 0; it < 8; ++it) {
            const int idx = it * 256 + tid;
            if (idx < KD * (WW / 4)) {              // 1944
                const int dx = idx / 24;
                const int x4 = idx - dx * 24;
                *reinterpret_cast<float4*>(outbase + (size_t)dx * HW + x4 * 4) = z;
            }
        }
        return;
    }

    // Union LDS: staging (2 x 6912 ush = 27648 B) overlapped with
    // band-folded sD (81x96 fp32 = 31104 B). Block LDS = 31104 B.
    __shared__ __align__(16) char smem[KD * WW * 4];
    unsigned short* sStage = reinterpret_cast<unsigned short*>(smem);
    unsigned short* sA = sStage;            // x1 row, [x][c-half]
    unsigned short* sB = sStage + CHUNK;    // x2 row, [x2][c-half]
    float*          sG = reinterpret_cast<float*>(smem);   // sD[dx][x] swizzled

    const unsigned short* wsA = ws + ((size_t)(b * HH + y ) * 2) * CHUNK;
    const unsigned short* wsB = ws + WS2_USH + ((size_t)(b * HH + y2) * 2) * CHUNK;

    const int lane = tid & 63;
    const int wave = tid >> 6;
    const int m0   = (wave >> 1) * 48;   // x2-tile base for this wave
    const int n0   = (wave & 1) * 48;    // x-tile base
    const int lr   = lane & 15;
    const int q    = lane >> 4;

    f32x4 acc[3][3];
    #pragma unroll
    for (int i = 0; i < 3; ++i)
        #pragma unroll
        for (int j = 0; j < 3; ++j)
            acc[i][j] = (f32x4){0.f, 0.f, 0.f, 0.f};

    for (int h = 0; h < 2; ++h) {
        if (h) __syncthreads();          // protect half-0 fragment reads
        const unsigned short* g1 = wsA + (size_t)h * CHUNK;
        const unsigned short* g2 = wsB + (size_t)h * CHUNK;
        #pragma unroll
        for (int it = 0; it < 7; ++it) {
            const int idx = it * 256 + tid;
            if (idx < 2 * (CHUNK / 8)) {                 // 1728
                const unsigned short* g = (idx < (CHUNK / 8))
                    ? g1 + (size_t)idx * 8
                    : g2 + (size_t)(idx - (CHUNK / 8)) * 8;
                gload16(g, sStage + (size_t)idx * 8);
            }
        }
        __syncthreads();                 // drains vmcnt before barrier

        mfma_half(sA, sB, m0, n0, lr, q, acc);
    }

    __syncthreads();                     // all fragment reads done; smem -> sD
    // D layout: col = lane&15 (=x), row = q*4+r (=x2 within tile).
    // Band-fold: dx = x2 - x + 40; keep 0..80. SCALE folded in here.
    // Swizzle ((dx>>2)&1)<<4 (words): q0/q1 hit disjoint 16-bank halves;
    // q2(q3) 2-way-aliases q0(q1) -> free (m136). Conflict-free write.
    #pragma unroll
    for (int i = 0; i < 3; ++i) {
        #pragma unroll
        for (int j = 0; j < 3; ++j) {
            const int col  = n0 + 16 * j + lr;
            const int rowb = m0 + 16 * i + q * 4;
            #pragma unroll
            for (int r = 0; r < 4; ++r) {
                const int dxv = (rowb + r) - col + MD;
                if ((unsigned)dxv < (unsigned)KD) {
                    const int w = (dxv * WW + col) ^ (((dxv >> 2) & 1) << 4);
                    sG[w] = acc[i][j][r] * SCALE;
                }
            }
        }
    }
    __syncthreads();

    // Emit 81x96 slab linearly: 1944 float4 items, contiguous ds_read_b128
    // (uniform 8 words/bank) + coalesced dwordx4 stores. Out-of-band entries
    // (x2 outside [0,96)) hold garbage -> masked to 0 per element.
    int dx = tid / 24;                   // word0 = 4*tid; dx = word0/96
    int x  = 4 * tid - dx * WW;
    #pragma unroll
    for (int it = 0; it < 8; ++it) {
        if (it < 7 || tid < 152) {       // 1944 = 7*256 + 152
            const int baddr = ((dx * WW + x) << 2) ^ (((dx >> 2) & 1) << 6);
            float4 v = *reinterpret_cast<const float4*>(smem + baddr);
            const int x2b = x + dx - MD;
            v.x = ((unsigned)(x2b + 0) < (unsigned)WW) ? v.x : 0.f;
            v.y = ((unsigned)(x2b + 1) < (unsigned)WW) ? v.y : 0.f;
            v.z = ((unsigned)(x2b + 2) < (unsigned)WW) ? v.z : 0.f;
            v.w = ((unsigned)(x2b + 3) < (unsigned)WW) ? v.w : 0.f;
            *reinterpret_cast<float4*>(outbase + (size_t)(dx * HW + x)) = v;
        }
        x += 64; dx += 10;               // advance 1024 words = 10 rows + 64
        if (x >= WW) { x -= WW; ++dx; }
    }
}

extern "C" void kernel_launch(void* const* d_in, const int* in_sizes, int n_in,
                              void* d_out, int out_size, void* d_ws, size_t ws_size,
                              hipStream_t stream) {
    const float* x1 = (const float*)d_in[0];
    const float* x2 = (const float*)d_in[1];
    float* out = (float*)d_out;
    unsigned short* ws = (unsigned short*)d_ws;

    hipLaunchKernelGGL(prepack, dim3(HH, 4, 2), dim3(256), 0, stream, x1, x2, ws);

    hipLaunchKernelGGL(corr_kernel, dim3(NWG), dim3(256), 0, stream, ws, out);
}

// Round 6
// 339.752 us; speedup vs baseline: 1.2505x; 1.0207x over previous
//
#include <hip/hip_runtime.h>

#define CH    128
#define HH    64
#define WW    96
#define MD    40
#define KD    81
#define HW    (HH*WW)          /* 6144 */
#define CHW   (CH*HW)
#define SCALE 0.08838834764831845f   /* 1/sqrt(128) */
#define LSTR  72               /* ushorts per row: 64 bf16 + 8 pad (16B-aligned rows) */
#define CHUNK (WW*LSTR)        /* 6912 ushorts = 13824 B per (b,y,h) per tensor */
#define WS2_USH ((size_t)2*HH*2*CHUNK)  /* x2 region offset in ushorts */
#define NWG   (HH*KD*2)        /* 10368 blocks */

typedef __attribute__((ext_vector_type(8))) short bf16x8;
typedef __attribute__((ext_vector_type(4))) float f32x4;

__device__ inline unsigned int pack2bf(float lo, float hi) {
    unsigned int a = __float_as_uint(lo), b = __float_as_uint(hi);
    a = (a + 0x7FFFu + ((a >> 16) & 1u)) >> 16;   // RTN bf16
    b = (b + 0x7FFFu + ((b >> 16) & 1u)) >> 16;
    return a | (b << 16);
}

__device__ __forceinline__ void gload16(const void* g, void* l) {
    __builtin_amdgcn_global_load_lds(
        (const __attribute__((address_space(1))) void*)g,
        (__attribute__((address_space(3))) void*)l, 16, 0, 0);
}

// ---------------------------------------------------------------------------
// Pre-pass: transpose+convert x1,x2 rows to bf16 workspace, [b][y][h][x][72].
// ---------------------------------------------------------------------------
__global__ __launch_bounds__(256) void prepack(
    const float* __restrict__ x1, const float* __restrict__ x2,
    unsigned short* __restrict__ ws)
{
    const int y = blockIdx.x;
    const int h = blockIdx.y & 1;
    const int t = blockIdx.y >> 1;
    const int b = blockIdx.z;

    const float* src = (t ? x2 : x1)
        + (size_t)b * CHW + (size_t)(h * 64) * HW + (size_t)y * WW;
    unsigned short* dst = ws + (size_t)t * WS2_USH
        + ((size_t)(b * HH + y) * 2 + h) * CHUNK;

    for (int j = threadIdx.x; j < 8 * WW; j += 256) {   // 3 iters
        const int cg = j / WW;                          // channel octet 0..7
        const int x  = j - cg * WW;
        const float* p = src + (size_t)(cg * 8) * HW + x;
        float f[8];
        #pragma unroll
        for (int i = 0; i < 8; ++i) f[i] = p[(size_t)i * HW];
        uint4 w;
        w.x = pack2bf(f[0], f[1]); w.y = pack2bf(f[2], f[3]);
        w.z = pack2bf(f[4], f[5]); w.w = pack2bf(f[6], f[7]);
        *reinterpret_cast<uint4*>(&dst[(size_t)x * LSTR + cg * 8]) = w;
    }
}

__device__ __forceinline__ void mfma_half(
    const unsigned short* sA, const unsigned short* sB,
    int m0, int n0, int lr, int q, f32x4 (&acc)[3][3])
{
    #pragma unroll
    for (int kk = 0; kk < 2; ++kk) {
        const int cl = kk * 32 + q * 8;
        bf16x8 af[3], bg[3];
        #pragma unroll
        for (int i = 0; i < 3; ++i)
            af[i] = *reinterpret_cast<const bf16x8*>(&sB[(m0 + 16 * i + lr) * LSTR + cl]);
        #pragma unroll
        for (int j = 0; j < 3; ++j)
            bg[j] = *reinterpret_cast<const bf16x8*>(&sA[(n0 + 16 * j + lr) * LSTR + cl]);
        #pragma unroll
        for (int i = 0; i < 3; ++i)
            #pragma unroll
            for (int j = 0; j < 3; ++j)
                acc[i][j] = __builtin_amdgcn_mfma_f32_16x16x32_bf16(
                    af[i], bg[j], acc[i][j], 0, 0, 0);
    }
}

// ---------------------------------------------------------------------------
// Main: NATURAL flat order (y fastest). bid%8 round-robin across XCDs gives
// each XCD the y = k (mod 8) class for EVERY dy:
//  - load balance: valid-block count per XCD equal to within +-1 per dy
//    (the R1-R4 chunked swizzle gave XCD1 ~1090 valid blocks vs 886 avg,
//     a ~1.23x makespan stretch -> removed);
//  - locality: live window per XCD = ~8 x1 rows + <=64 x2 rows ~ 2 MB,
//    L2-resident without chunking.
// G written band-folded as sD[dx][x] (dx = x2-x+40, 0..80 kept), XOR-swizzled
// (((dx>>2)&1)<<4 words) -> conflict-free write; emit is a LINEAR
// ds_read_b128 + float4 store (8 iters).
// ---------------------------------------------------------------------------
__global__ __launch_bounds__(256, 4) void corr_kernel(
    const unsigned short* __restrict__ ws, float* __restrict__ out)
{
    const int wg  = blockIdx.x;        // natural order: balanced + local
    const int b   = (wg >= HH * KD) ? 1 : 0;
    const int rem = wg - b * (HH * KD);
    const int dy  = rem >> 6;          // (b, dy, y) with y fastest (HH=64)
    const int y   = rem & 63;
    const int tid = threadIdx.x;

    float* outbase = out + ((size_t)b * (KD * KD) + (size_t)dy * KD) * HW
                         + (size_t)y * WW;

    const int y2 = y + dy - MD;
    if (y2 < 0 || y2 >= HH) {
        const float4 z = make_float4(0.f, 0.f, 0.f, 0.f);
        #pragma unroll
        for (int it = 0; it < 8; ++it) {
            const int idx = it * 256 + tid;
            if (idx < KD * (WW / 4)) {              // 1944
                const int dx = idx / 24;
                const int x4 = idx - dx * 24;
                *reinterpret_cast<float4*>(outbase + (size_t)dx * HW + x4 * 4) = z;
            }
        }
        return;
    }

    // Union LDS: staging (2 x 6912 ush = 27648 B) overlapped with
    // band-folded sD (81x96 fp32 = 31104 B). Block LDS = 31104 B.
    __shared__ __align__(16) char smem[KD * WW * 4];
    unsigned short* sStage = reinterpret_cast<unsigned short*>(smem);
    unsigned short* sA = sStage;            // x1 row, [x][c-half]
    unsigned short* sB = sStage + CHUNK;    // x2 row, [x2][c-half]
    float*          sG = reinterpret_cast<float*>(smem);   // sD[dx][x] swizzled

    const unsigned short* wsA = ws + ((size_t)(b * HH + y ) * 2) * CHUNK;
    const unsigned short* wsB = ws + WS2_USH + ((size_t)(b * HH + y2) * 2) * CHUNK;

    const int lane = tid & 63;
    const int wave = tid >> 6;
    const int m0   = (wave >> 1) * 48;   // x2-tile base for this wave
    const int n0   = (wave & 1) * 48;    // x-tile base
    const int lr   = lane & 15;
    const int q    = lane >> 4;

    f32x4 acc[3][3];
    #pragma unroll
    for (int i = 0; i < 3; ++i)
        #pragma unroll
        for (int j = 0; j < 3; ++j)
            acc[i][j] = (f32x4){0.f, 0.f, 0.f, 0.f};

    for (int h = 0; h < 2; ++h) {
        if (h) __syncthreads();          // protect half-0 fragment reads
        const unsigned short* g1 = wsA + (size_t)h * CHUNK;
        const unsigned short* g2 = wsB + (size_t)h * CHUNK;
        #pragma unroll
        for (int it = 0; it < 7; ++it) {
            const int idx = it * 256 + tid;
            if (idx < 2 * (CHUNK / 8)) {                 // 1728
                const unsigned short* g = (idx < (CHUNK / 8))
                    ? g1 + (size_t)idx * 8
                    : g2 + (size_t)(idx - (CHUNK / 8)) * 8;
                gload16(g, sStage + (size_t)idx * 8);
            }
        }
        __syncthreads();                 // drains vmcnt before barrier

        mfma_half(sA, sB, m0, n0, lr, q, acc);
    }

    __syncthreads();                     // all fragment reads done; smem -> sD
    // D layout: col = lane&15 (=x), row = q*4+r (=x2 within tile).
    // Band-fold: dx = x2 - x + 40; keep 0..80. SCALE folded in here.
    // Swizzle ((dx>>2)&1)<<4 (words): q0/q1 hit disjoint 16-bank halves;
    // q2(q3) 2-way-aliases q0(q1) -> free (m136). Conflict-free write.
    #pragma unroll
    for (int i = 0; i < 3; ++i) {
        #pragma unroll
        for (int j = 0; j < 3; ++j) {
            const int col  = n0 + 16 * j + lr;
            const int rowb = m0 + 16 * i + q * 4;
            #pragma unroll
            for (int r = 0; r < 4; ++r) {
                const int dxv = (rowb + r) - col + MD;
                if ((unsigned)dxv < (unsigned)KD) {
                    const int w = (dxv * WW + col) ^ (((dxv >> 2) & 1) << 4);
                    sG[w] = acc[i][j][r] * SCALE;
                }
            }
        }
    }
    __syncthreads();

    // Emit 81x96 slab linearly: 1944 float4 items, contiguous ds_read_b128
    // (uniform 8 words/bank) + coalesced dwordx4 stores. Out-of-band entries
    // (x2 outside [0,96)) hold garbage -> masked to 0 per element.
    int dx = tid / 24;                   // word0 = 4*tid; dx = word0/96
    int x  = 4 * tid - dx * WW;
    #pragma unroll
    for (int it = 0; it < 8; ++it) {
        if (it < 7 || tid < 152) {       // 1944 = 7*256 + 152
            const int baddr = ((dx * WW + x) << 2) ^ (((dx >> 2) & 1) << 6);
            float4 v = *reinterpret_cast<const float4*>(smem + baddr);
            const int x2b = x + dx - MD;
            v.x = ((unsigned)(x2b + 0) < (unsigned)WW) ? v.x : 0.f;
            v.y = ((unsigned)(x2b + 1) < (unsigned)WW) ? v.y : 0.f;
            v.z = ((unsigned)(x2b + 2) < (unsigned)WW) ? v.z : 0.f;
            v.w = ((unsigned)(x2b + 3) < (unsigned)WW) ? v.w : 0.f;
            *reinterpret_cast<float4*>(outbase + (size_t)(dx * HW + x)) = v;
        }
        x += 64; dx += 10;               // advance 1024 words = 10 rows + 64
        if (x >= WW) { x -= WW; ++dx; }
    }
}

extern "C" void kernel_launch(void* const* d_in, const int* in_sizes, int n_in,
                              void* d_out, int out_size, void* d_ws, size_t ws_size,
                              hipStream_t stream) {
    const float* x1 = (const float*)d_in[0];
    const float* x2 = (const float*)d_in[1];
    float* out = (float*)d_out;
    unsigned short* ws = (unsigned short*)d_ws;

    hipLaunchKernelGGL(prepack, dim3(HH, 4, 2), dim3(256), 0, stream, x1, x2, ws);

    hipLaunchKernelGGL(corr_kernel, dim3(NWG), dim3(256), 0, stream, ws, out);
}